// Round 1
// baseline (344.341 us; speedup 1.0000x reference)
//
#include <hip/hip_runtime.h>

typedef __attribute__((ext_vector_type(8))) short short8;
typedef __attribute__((ext_vector_type(4))) float f32x4;

__device__ __forceinline__ unsigned short f2bf(float f) {
    unsigned u = __builtin_bit_cast(unsigned, f);
    u += 0x7FFFu + ((u >> 16) & 1u);
    return (unsigned short)(u >> 16);
}
__device__ __forceinline__ float bf2f(unsigned short b) {
    unsigned u = ((unsigned)b) << 16;
    return __builtin_bit_cast(float, u);
}
__device__ __forceinline__ short8 ld_frag(const uint4* p, int idx16) {
    return __builtin_bit_cast(short8, p[idx16]);
}

// ---------------- RoPE table: cos/sin [2048][32] fp32 ----------------
__global__ void rope_table_kernel(float* cosT, float* sinT) {
    int idx = blockIdx.x * 256 + threadIdx.x;     // 65536 total
    int s = idx >> 5, i = idx & 31;
    float inv = powf(10000.f, -(float)i / 32.f);
    float ang = (float)s * inv;
    cosT[idx] = cosf(ang);
    sinT[idx] = sinf(ang);
}

// ---------------- cast x (fp32) -> bf16, 4 elems/thread ----------------
__global__ void cast_x_kernel(const float* __restrict__ x, unsigned short* __restrict__ xb) {
    int i = blockIdx.x * 256 + threadIdx.x;       // 1M threads
    float4 v = reinterpret_cast<const float4*>(x)[i];
    ushort4 o;
    o.x = f2bf(v.x); o.y = f2bf(v.y); o.z = f2bf(v.z); o.w = f2bf(v.w);
    reinterpret_cast<ushort4*>(xb)[i] = o;
}

// ---------------- transpose + cast: in [R][C] fp32 -> out [C][R] bf16 ----------------
__global__ void transpose_cast_kernel(const float* __restrict__ in, unsigned short* __restrict__ out,
                                      int R, int C) {
    __shared__ float t[32][33];
    int c0 = blockIdx.x * 32, r0 = blockIdx.y * 32;
    int tx = threadIdx.x, ty = threadIdx.y;       // 32 x 8
    for (int i = 0; i < 4; ++i)
        t[ty + i * 8][tx] = in[(size_t)(r0 + ty + i * 8) * C + c0 + tx];
    __syncthreads();
    for (int i = 0; i < 4; ++i)
        out[(size_t)(c0 + ty + i * 8) * R + r0 + tx] = f2bf(t[tx][ty + i * 8]);
}

// ---------------- bf16 GEMM: A[M][K] x Bt[N][K]^T -> C[M][N] ----------------
// 128x128 tile, BK=32, 4 waves (2x2), each wave 64x64 = 4x4 16x16 frags.
template <bool OUT_BF16>
__global__ __launch_bounds__(256) void gemm_bt_kernel(const unsigned short* __restrict__ A,
                                                      const unsigned short* __restrict__ Bt,
                                                      void* __restrict__ Cout,
                                                      int M, int N, int K) {
    __shared__ __align__(16) unsigned short As[128 * 32];
    __shared__ __align__(16) unsigned short Bs[128 * 32];
    int tid = threadIdx.x;
    int lane = tid & 63;
    int wid = tid >> 6;
    int wm = wid >> 1, wn = wid & 1;
    int m0 = blockIdx.y * 128, n0 = blockIdx.x * 128;
    int rq = lane >> 4, cl = lane & 15;

    f32x4 acc[4][4] = {};
    const uint4* Ag = reinterpret_cast<const uint4*>(A);
    const uint4* Bg = reinterpret_cast<const uint4*>(Bt);
    uint4* As4 = reinterpret_cast<uint4*>(As);
    uint4* Bs4 = reinterpret_cast<uint4*>(Bs);

    for (int k0 = 0; k0 < K; k0 += 32) {
        __syncthreads();
        // stage: 512 chunks of 16B each for A and B (2 per thread each)
        {
            int c = tid;
            int r = c >> 2, cc = c & 3;
            As4[c] = Ag[((size_t)(m0 + r) * K + k0 + cc * 8) >> 3];
            Bs4[c] = Bg[((size_t)(n0 + r) * K + k0 + cc * 8) >> 3];
            c = tid + 256;
            r = c >> 2; cc = c & 3;
            As4[c] = Ag[((size_t)(m0 + r) * K + k0 + cc * 8) >> 3];
            Bs4[c] = Bg[((size_t)(n0 + r) * K + k0 + cc * 8) >> 3];
        }
        __syncthreads();
        short8 af[4], bfr[4];
        for (int mf = 0; mf < 4; ++mf) {
            int row = wm * 64 + mf * 16 + cl;
            af[mf] = ld_frag(As4, row * 4 + rq);
        }
        for (int nf = 0; nf < 4; ++nf) {
            int row = wn * 64 + nf * 16 + cl;
            bfr[nf] = ld_frag(Bs4, row * 4 + rq);
        }
        for (int mf = 0; mf < 4; ++mf)
            for (int nf = 0; nf < 4; ++nf)
                acc[mf][nf] = __builtin_amdgcn_mfma_f32_16x16x32_bf16(af[mf], bfr[nf], acc[mf][nf], 0, 0, 0);
    }
    // epilogue
    for (int mf = 0; mf < 4; ++mf)
        for (int nf = 0; nf < 4; ++nf)
            for (int r = 0; r < 4; ++r) {
                size_t row = m0 + wm * 64 + mf * 16 + rq * 4 + r;
                size_t col = n0 + wn * 64 + nf * 16 + cl;
                float v = acc[mf][nf][r];
                if (OUT_BF16)
                    ((unsigned short*)Cout)[row * N + col] = f2bf(v);
                else
                    ((float*)Cout)[row * N + col] = v;
            }
}

// ---------------- RoPE + split: qkv bf16 [4096][3072] -> Q,K [B,H,S,64] rope'd, V^T [B,H,64,S] ----------------
__global__ void rope_split_kernel(const unsigned short* __restrict__ qkv,
                                  const float* __restrict__ cosT, const float* __restrict__ sinT,
                                  unsigned short* __restrict__ Qb, unsigned short* __restrict__ Kb,
                                  unsigned short* __restrict__ VT) {
    int t = blockIdx.x * 256 + threadIdx.x;       // 2^22 threads
    int d = t & 63;
    int h = (t >> 6) & 15;
    int s = (t >> 10) & 2047;
    int b = t >> 21;
    size_t rowb = ((size_t)(b * 2048 + s)) * 3072;
    int col = h * 64 + d;
    int f = d & 31;
    float cs = cosT[s * 32 + f], sn = sinT[s * 32 + f];
    int d2 = (d < 32) ? d + 32 : d - 32;

    float q  = bf2f(qkv[rowb + col]);
    float qp = bf2f(qkv[rowb + h * 64 + d2]);
    float qo = (d < 32) ? q * cs - qp * sn : q * cs + qp * sn;
    float k  = bf2f(qkv[rowb + 1024 + col]);
    float kp = bf2f(qkv[rowb + 1024 + h * 64 + d2]);
    float ko = (d < 32) ? k * cs - kp * sn : k * cs + kp * sn;
    unsigned short v = qkv[rowb + 2048 + col];

    size_t ho = (size_t)(b * 16 + h);
    Qb[(ho * 2048 + s) * 64 + d] = f2bf(qo);
    Kb[(ho * 2048 + s) * 64 + d] = f2bf(ko);
    VT[(ho * 64 + d) * 2048 + s] = v;
}

// ---------------- flash attention: 1 wave per 16 q-rows, KVB=32 ----------------
__global__ __launch_bounds__(64) void flash_attn_kernel(const unsigned short* __restrict__ Qb,
                                                        const unsigned short* __restrict__ Kb,
                                                        const unsigned short* __restrict__ VT,
                                                        unsigned short* __restrict__ Oattn) {
    const int S = 2048;
    int lane = threadIdx.x;
    int q0 = blockIdx.x * 16;
    int h = blockIdx.y, b = blockIdx.z;
    size_t headOff = ((size_t)(b * 16 + h)) * S * 64;
    const uint4* Q4 = reinterpret_cast<const uint4*>(Qb + headOff);
    const uint4* K4 = reinterpret_cast<const uint4*>(Kb + headOff);
    const uint4* V4 = reinterpret_cast<const uint4*>(VT + headOff);  // [64][S]
    __shared__ __align__(16) unsigned short p_lds[16 * 32];

    int rq = lane >> 4, cl = lane & 15;
    short8 aq[2];
    for (int c = 0; c < 2; ++c)
        aq[c] = ld_frag(Q4, ((q0 + cl) * 64 + c * 32 + rq * 8) >> 3);

    float m[4], l[4];
    for (int r = 0; r < 4; ++r) { m[r] = -INFINITY; l[r] = 0.f; }
    f32x4 acc[4] = {};
    const float sl2e = 0.125f * 1.44269504088896f;  // scale * log2(e)

    int nk = (q0 + 16 + 31) / 32;
    for (int kt = 0; kt < nk; ++kt) {
        int kv0 = kt * 32;
        f32x4 sc[2] = {};
        for (int f = 0; f < 2; ++f) {
            short8 bk0 = ld_frag(K4, ((kv0 + f * 16 + cl) * 64 + 0  + rq * 8) >> 3);
            short8 bk1 = ld_frag(K4, ((kv0 + f * 16 + cl) * 64 + 32 + rq * 8) >> 3);
            sc[f] = __builtin_amdgcn_mfma_f32_16x16x32_bf16(aq[0], bk0, sc[f], 0, 0, 0);
            sc[f] = __builtin_amdgcn_mfma_f32_16x16x32_bf16(aq[1], bk1, sc[f], 0, 0, 0);
        }
        float p0[4], p1[4], rmax[4], rsum[4], alpha[4];
        for (int r = 0; r < 4; ++r) {
            int qrow = q0 + rq * 4 + r;
            p0[r] = (kv0 + cl      <= qrow) ? sc[0][r] * sl2e : -INFINITY;
            p1[r] = (kv0 + 16 + cl <= qrow) ? sc[1][r] * sl2e : -INFINITY;
            rmax[r] = fmaxf(p0[r], p1[r]);
        }
        for (int d = 1; d < 16; d <<= 1)
            for (int r = 0; r < 4; ++r)
                rmax[r] = fmaxf(rmax[r], __shfl_xor(rmax[r], d));
        for (int r = 0; r < 4; ++r) {
            float mn = fmaxf(m[r], rmax[r]);
            alpha[r] = exp2f(m[r] - mn);
            m[r] = mn;
            p0[r] = exp2f(p0[r] - mn);
            p1[r] = exp2f(p1[r] - mn);
            rsum[r] = p0[r] + p1[r];
        }
        for (int d = 1; d < 16; d <<= 1)
            for (int r = 0; r < 4; ++r)
                rsum[r] += __shfl_xor(rsum[r], d);
        for (int r = 0; r < 4; ++r) l[r] = l[r] * alpha[r] + rsum[r];
        for (int nf = 0; nf < 4; ++nf) {
            f32x4 t = acc[nf];
            for (int r = 0; r < 4; ++r) t[r] *= alpha[r];
            acc[nf] = t;
        }
        // P tile -> LDS (transpose to A-operand layout)
        __syncthreads();
        for (int r = 0; r < 4; ++r) {
            p_lds[(rq * 4 + r) * 32 + cl]      = f2bf(p0[r]);
            p_lds[(rq * 4 + r) * 32 + 16 + cl] = f2bf(p1[r]);
        }
        __syncthreads();
        short8 pa = ld_frag(reinterpret_cast<const uint4*>(p_lds), cl * 4 + rq);
        for (int nf = 0; nf < 4; ++nf) {
            short8 bv = ld_frag(V4, ((nf * 16 + cl) * S + kv0 + rq * 8) >> 3);
            acc[nf] = __builtin_amdgcn_mfma_f32_16x16x32_bf16(pa, bv, acc[nf], 0, 0, 0);
        }
    }
    // epilogue: write [B,S,D] bf16
    for (int nf = 0; nf < 4; ++nf)
        for (int r = 0; r < 4; ++r) {
            int qrow = q0 + rq * 4 + r;
            float v = acc[nf][r] / l[r];
            Oattn[((size_t)(b * 2048 + qrow)) * 1024 + h * 64 + nf * 16 + cl] = f2bf(v);
        }
}

extern "C" void kernel_launch(void* const* d_in, const int* in_sizes, int n_in,
                              void* d_out, int out_size, void* d_ws, size_t ws_size,
                              hipStream_t stream) {
    const float* x    = (const float*)d_in[0];   // [2,2048,1024]
    const float* wqkv = (const float*)d_in[1];   // [1024,3072]
    const float* wout = (const float*)d_in[2];   // [1024,1024]
    // d_in[3] = causal mask (ignored; applied analytically)

    char* ws = (char*)d_ws;
    unsigned short* xb    = (unsigned short*)(ws);                       // 8 MB
    unsigned short* wqkvT = (unsigned short*)(ws + (8ull  << 20));       // 6 MB
    unsigned short* woutT = (unsigned short*)(ws + (14ull << 20));       // 2 MB
    unsigned short* qkv   = (unsigned short*)(ws + (16ull << 20));       // 24 MB
    unsigned short* Qb    = (unsigned short*)(ws + (40ull << 20));       // 8 MB
    unsigned short* Kb    = (unsigned short*)(ws + (48ull << 20));       // 8 MB
    unsigned short* VT    = (unsigned short*)(ws + (56ull << 20));       // 8 MB
    unsigned short* Oat   = (unsigned short*)(ws + (64ull << 20));       // 8 MB
    float* cosT           = (float*)(ws + (72ull << 20));                // 256 KB
    float* sinT           = (float*)(ws + (72ull << 20) + (256u << 10)); // 256 KB

    rope_table_kernel<<<256, 256, 0, stream>>>(cosT, sinT);
    cast_x_kernel<<<4096, 256, 0, stream>>>(x, xb);
    transpose_cast_kernel<<<dim3(96, 32), dim3(32, 8), 0, stream>>>(wqkv, wqkvT, 1024, 3072);
    transpose_cast_kernel<<<dim3(32, 32), dim3(32, 8), 0, stream>>>(wout, woutT, 1024, 1024);
    gemm_bt_kernel<true><<<dim3(24, 32), 256, 0, stream>>>(xb, wqkvT, qkv, 4096, 3072, 1024);
    rope_split_kernel<<<16384, 256, 0, stream>>>(qkv, cosT, sinT, Qb, Kb, VT);
    flash_attn_kernel<<<dim3(128, 16, 2), 64, 0, stream>>>(Qb, Kb, VT, Oat);
    gemm_bt_kernel<false><<<dim3(8, 32), 256, 0, stream>>>(Oat, woutT, d_out, 4096, 1024, 1024);
}

// Round 2
// 205.278 us; speedup vs baseline: 1.6774x; 1.6774x over previous
//
#include <hip/hip_runtime.h>

typedef __attribute__((ext_vector_type(8))) short short8;
typedef __attribute__((ext_vector_type(4))) float f32x4;
typedef __attribute__((ext_vector_type(16))) float f32x16;

__device__ __forceinline__ unsigned short f2bf(float f) {
    unsigned u = __builtin_bit_cast(unsigned, f);
    u += 0x7FFFu + ((u >> 16) & 1u);
    return (unsigned short)(u >> 16);
}
__device__ __forceinline__ float bf2f(unsigned short b) {
    unsigned u = ((unsigned)b) << 16;
    return __builtin_bit_cast(float, u);
}
__device__ __forceinline__ short8 ld_frag(const uint4* p, int idx16) {
    return __builtin_bit_cast(short8, p[idx16]);
}
__device__ __forceinline__ unsigned packbf(float a, float b) {
    return (unsigned)f2bf(a) | ((unsigned)f2bf(b) << 16);
}

// ---------------- RoPE table: cos/sin [2048][32] fp32 ----------------
__global__ void rope_table_kernel(float* cosT, float* sinT) {
    int idx = blockIdx.x * 256 + threadIdx.x;     // 65536 total
    int s = idx >> 5, i = idx & 31;
    float inv = powf(10000.f, -(float)i / 32.f);
    float ang = (float)s * inv;
    cosT[idx] = cosf(ang);
    sinT[idx] = sinf(ang);
}

// ---------------- cast x (fp32) -> bf16, 4 elems/thread ----------------
__global__ void cast_x_kernel(const float* __restrict__ x, unsigned short* __restrict__ xb) {
    int i = blockIdx.x * 256 + threadIdx.x;       // 1M threads
    float4 v = reinterpret_cast<const float4*>(x)[i];
    ushort4 o;
    o.x = f2bf(v.x); o.y = f2bf(v.y); o.z = f2bf(v.z); o.w = f2bf(v.w);
    reinterpret_cast<ushort4*>(xb)[i] = o;
}

// ---------------- transpose + cast: in [R][C] fp32 -> out [C][R] bf16 ----------------
__global__ void transpose_cast_kernel(const float* __restrict__ in, unsigned short* __restrict__ out,
                                      int R, int C) {
    __shared__ float t[32][33];
    int c0 = blockIdx.x * 32, r0 = blockIdx.y * 32;
    int tx = threadIdx.x, ty = threadIdx.y;       // 32 x 8
    for (int i = 0; i < 4; ++i)
        t[ty + i * 8][tx] = in[(size_t)(r0 + ty + i * 8) * C + c0 + tx];
    __syncthreads();
    for (int i = 0; i < 4; ++i)
        out[(size_t)(c0 + ty + i * 8) * R + r0 + tx] = f2bf(t[tx][ty + i * 8]);
}

// ---------------- bf16 GEMM: A[M][K] x Bt[N][K]^T -> C[M][N] ----------------
template <bool OUT_BF16>
__global__ __launch_bounds__(256) void gemm_bt_kernel(const unsigned short* __restrict__ A,
                                                      const unsigned short* __restrict__ Bt,
                                                      void* __restrict__ Cout,
                                                      int M, int N, int K) {
    __shared__ __align__(16) unsigned short As[128 * 32];
    __shared__ __align__(16) unsigned short Bs[128 * 32];
    int tid = threadIdx.x;
    int lane = tid & 63;
    int wid = tid >> 6;
    int wm = wid >> 1, wn = wid & 1;
    int m0 = blockIdx.y * 128, n0 = blockIdx.x * 128;
    int rq = lane >> 4, cl = lane & 15;

    f32x4 acc[4][4] = {};
    const uint4* Ag = reinterpret_cast<const uint4*>(A);
    const uint4* Bg = reinterpret_cast<const uint4*>(Bt);
    uint4* As4 = reinterpret_cast<uint4*>(As);
    uint4* Bs4 = reinterpret_cast<uint4*>(Bs);

    for (int k0 = 0; k0 < K; k0 += 32) {
        __syncthreads();
        {
            int c = tid;
            int r = c >> 2, cc = c & 3;
            As4[c] = Ag[((size_t)(m0 + r) * K + k0 + cc * 8) >> 3];
            Bs4[c] = Bg[((size_t)(n0 + r) * K + k0 + cc * 8) >> 3];
            c = tid + 256;
            r = c >> 2; cc = c & 3;
            As4[c] = Ag[((size_t)(m0 + r) * K + k0 + cc * 8) >> 3];
            Bs4[c] = Bg[((size_t)(n0 + r) * K + k0 + cc * 8) >> 3];
        }
        __syncthreads();
        short8 af[4], bfr[4];
        for (int mf = 0; mf < 4; ++mf) {
            int row = wm * 64 + mf * 16 + cl;
            af[mf] = ld_frag(As4, row * 4 + rq);
        }
        for (int nf = 0; nf < 4; ++nf) {
            int row = wn * 64 + nf * 16 + cl;
            bfr[nf] = ld_frag(Bs4, row * 4 + rq);
        }
        for (int mf = 0; mf < 4; ++mf)
            for (int nf = 0; nf < 4; ++nf)
                acc[mf][nf] = __builtin_amdgcn_mfma_f32_16x16x32_bf16(af[mf], bfr[nf], acc[mf][nf], 0, 0, 0);
    }
    for (int mf = 0; mf < 4; ++mf)
        for (int nf = 0; nf < 4; ++nf)
            for (int r = 0; r < 4; ++r) {
                size_t row = m0 + wm * 64 + mf * 16 + rq * 4 + r;
                size_t col = n0 + wn * 64 + nf * 16 + cl;
                float v = acc[mf][nf][r];
                if (OUT_BF16)
                    ((unsigned short*)Cout)[row * N + col] = f2bf(v);
                else
                    ((float*)Cout)[row * N + col] = v;
            }
}

// ---------------- RoPE + split ----------------
__global__ void rope_split_kernel(const unsigned short* __restrict__ qkv,
                                  const float* __restrict__ cosT, const float* __restrict__ sinT,
                                  unsigned short* __restrict__ Qb, unsigned short* __restrict__ Kb,
                                  unsigned short* __restrict__ VT) {
    int t = blockIdx.x * 256 + threadIdx.x;       // 2^22 threads
    int d = t & 63;
    int h = (t >> 6) & 15;
    int s = (t >> 10) & 2047;
    int b = t >> 21;
    size_t rowb = ((size_t)(b * 2048 + s)) * 3072;
    int col = h * 64 + d;
    int f = d & 31;
    float cs = cosT[s * 32 + f], sn = sinT[s * 32 + f];
    int d2 = (d < 32) ? d + 32 : d - 32;

    float q  = bf2f(qkv[rowb + col]);
    float qp = bf2f(qkv[rowb + h * 64 + d2]);
    float qo = (d < 32) ? q * cs - qp * sn : q * cs + qp * sn;
    float k  = bf2f(qkv[rowb + 1024 + col]);
    float kp = bf2f(qkv[rowb + 1024 + h * 64 + d2]);
    float ko = (d < 32) ? k * cs - kp * sn : k * cs + kp * sn;
    unsigned short v = qkv[rowb + 2048 + col];

    size_t ho = (size_t)(b * 16 + h);
    Qb[(ho * 2048 + s) * 64 + d] = f2bf(qo);
    Kb[(ho * 2048 + s) * 64 + d] = f2bf(ko);
    VT[(ho * 64 + d) * 2048 + s] = v;
}

// ---------------- flash attention: 4 waves x 32 q-rows, KVBLK=64, swapped-operand 32x32 MFMA ----------------
__device__ __forceinline__ short8 lds_frag(const unsigned short* base, int row, int colByte) {
    return __builtin_bit_cast(short8,
        *reinterpret_cast<const uint4*>(reinterpret_cast<const char*>(base) + row * 128 +
                                        (colByte ^ ((row & 7) << 4))));
}

__global__ __launch_bounds__(256) void flash_attn_kernel(const unsigned short* __restrict__ Qb,
                                                         const unsigned short* __restrict__ Kb,
                                                         const unsigned short* __restrict__ VT,
                                                         unsigned short* __restrict__ Oattn) {
    const int S = 2048;
    __shared__ __align__(16) unsigned short Ks[64 * 64];
    __shared__ __align__(16) unsigned short Vs[64 * 64];
    int tid = threadIdx.x, lane = tid & 63, w = tid >> 6;
    int chunk = 15 - blockIdx.x;                  // heavy chunks dispatch first (LPT)
    int h = blockIdx.y, b = blockIdx.z;
    int q0 = chunk * 128;
    size_t headOff = ((size_t)(b * 16 + h)) * S * 64;
    const unsigned short* Kg = Kb + headOff;
    const unsigned short* Vg = VT + headOff;      // [64][S]
    int l31 = lane & 31, hi = lane >> 5;
    int qw = q0 + w * 32;
    int qrow = qw + l31;

    // Q fragments in registers: qf[c] holds Q[qrow][c*16 + hi*8 + j]
    short8 qf[4];
    {
        const uint4* Qg4 = reinterpret_cast<const uint4*>(Qb + headOff);
        for (int c = 0; c < 4; ++c)
            qf[c] = ld_frag(Qg4, qrow * 8 + c * 2 + hi);
    }

    f32x16 oacc0 = {}, oacc1 = {};
    float m = -INFINITY, l = 0.f;
    const float sl2e = 0.125f * 1.44269504088896f;
    int nk = (q0 + 128) / 64;
    int qmax_w = qw + 32;

    for (int kt = 0; kt < nk; ++kt) {
        int kv0 = kt * 64;
        __syncthreads();
        // stage K tile [64 kv][64 d] and V^T tile [64 d][64 kv], XOR-swizzled
        {
            const uint4* Kg4 = reinterpret_cast<const uint4*>(Kg);
            #pragma unroll
            for (int i = 0; i < 2; ++i) {
                int c = tid + i * 256;
                int r = c >> 3, c8 = c & 7;
                uint4 kval = Kg4[((kv0 + r) * 64 + c8 * 8) >> 3];
                uint4 vval = *reinterpret_cast<const uint4*>(Vg + (size_t)r * S + kv0 + c8 * 8);
                int sw = (c8 * 16) ^ ((r & 7) << 4);
                *reinterpret_cast<uint4*>(reinterpret_cast<char*>(Ks) + r * 128 + sw) = kval;
                *reinterpret_cast<uint4*>(reinterpret_cast<char*>(Vs) + r * 128 + sw) = vval;
            }
        }
        __syncthreads();
        if (kv0 >= qmax_w) continue;              // wave fully masked for this tile

        // QK^T (swapped): s0/s1 = S^T[kv][q], kv = kv0 + {0..31}/{32..63}
        f32x16 s0 = {}, s1 = {};
        #pragma unroll
        for (int c = 0; c < 4; ++c) {
            short8 a0 = lds_frag(Ks, l31, c * 32 + hi * 16);
            short8 a1 = lds_frag(Ks, 32 + l31, c * 32 + hi * 16);
            s0 = __builtin_amdgcn_mfma_f32_32x32x16_bf16(a0, qf[c], s0, 0, 0, 0);
            s1 = __builtin_amdgcn_mfma_f32_32x32x16_bf16(a1, qf[c], s1, 0, 0, 0);
        }

        // scale + mask + tile max (lane holds 32 scores for q = qrow)
        float tm = -INFINITY;
        if (kv0 + 63 <= qw) {                     // fully unmasked for the wave
            #pragma unroll
            for (int r = 0; r < 16; ++r) {
                s0[r] *= sl2e; s1[r] *= sl2e;
                tm = fmaxf(tm, fmaxf(s0[r], s1[r]));
            }
        } else {
            #pragma unroll
            for (int r = 0; r < 16; ++r) {
                int kva = kv0 + (r & 3) + 8 * (r >> 2) + 4 * hi;
                float v0 = (kva <= qrow) ? s0[r] * sl2e : -INFINITY;
                float v1 = (kva + 32 <= qrow) ? s1[r] * sl2e : -INFINITY;
                s0[r] = v0; s1[r] = v1;
                tm = fmaxf(tm, fmaxf(v0, v1));
            }
        }
        tm = fmaxf(tm, __shfl_xor(tm, 32));
        float mn = fmaxf(m, tm);
        float al = exp2f(m - mn);
        m = mn;
        float rs = 0.f;
        #pragma unroll
        for (int r = 0; r < 16; ++r) {
            s0[r] = exp2f(s0[r] - mn);
            s1[r] = exp2f(s1[r] - mn);
            rs += s0[r] + s1[r];
        }
        rs += __shfl_xor(rs, 32);
        l = l * al + rs;
        #pragma unroll
        for (int r = 0; r < 16; ++r) { oacc0[r] *= al; oacc1[r] *= al; }

        // P -> bf16 B-fragments via pack + half-wave exchange
        unsigned wd[16], xd[16];
        #pragma unroll
        for (int i = 0; i < 8; ++i) {
            wd[i]     = packbf(s0[2 * i], s0[2 * i + 1]);
            wd[i + 8] = packbf(s1[2 * i], s1[2 * i + 1]);
        }
        #pragma unroll
        for (int i = 0; i < 16; ++i) xd[i] = __shfl_xor((int)wd[i], 32);
        short8 pb[4];
        #pragma unroll
        for (int s = 0; s < 2; ++s) {
            int o = s * 8;
            uint4 lo0 = {wd[o + 0], wd[o + 1], xd[o + 0], xd[o + 1]};
            uint4 hi0 = {xd[o + 2], xd[o + 3], wd[o + 2], wd[o + 3]};
            uint4 lo1 = {wd[o + 4], wd[o + 5], xd[o + 4], xd[o + 5]};
            uint4 hi1 = {xd[o + 6], xd[o + 7], wd[o + 6], wd[o + 7]};
            pb[2 * s]     = __builtin_bit_cast(short8, hi ? hi0 : lo0);
            pb[2 * s + 1] = __builtin_bit_cast(short8, hi ? hi1 : lo1);
        }

        // PV (swapped): oacc = V^T x P^T, O^T[d][q]
        #pragma unroll
        for (int t = 0; t < 4; ++t) {
            short8 a0 = lds_frag(Vs, l31, t * 32 + hi * 16);
            short8 a1 = lds_frag(Vs, 32 + l31, t * 32 + hi * 16);
            oacc0 = __builtin_amdgcn_mfma_f32_32x32x16_bf16(a0, pb[t], oacc0, 0, 0, 0);
            oacc1 = __builtin_amdgcn_mfma_f32_32x32x16_bf16(a1, pb[t], oacc1, 0, 0, 0);
        }
    }

    // epilogue: out[qrow][d] = oacc[d][qrow] / l
    float invl = 1.f / l;
    size_t orow = ((size_t)(b * 2048 + qrow)) * 1024 + h * 64;
    #pragma unroll
    for (int du = 0; du < 2; ++du) {
        const f32x16& oa = du ? oacc1 : oacc0;
        #pragma unroll
        for (int g = 0; g < 4; ++g) {
            ushort4 o;
            o.x = f2bf(oa[4 * g + 0] * invl);
            o.y = f2bf(oa[4 * g + 1] * invl);
            o.z = f2bf(oa[4 * g + 2] * invl);
            o.w = f2bf(oa[4 * g + 3] * invl);
            int d = du * 32 + 4 * hi + 8 * g;
            *reinterpret_cast<ushort4*>(Oattn + orow + d) = o;
        }
    }
}

extern "C" void kernel_launch(void* const* d_in, const int* in_sizes, int n_in,
                              void* d_out, int out_size, void* d_ws, size_t ws_size,
                              hipStream_t stream) {
    const float* x    = (const float*)d_in[0];   // [2,2048,1024]
    const float* wqkv = (const float*)d_in[1];   // [1024,3072]
    const float* wout = (const float*)d_in[2];   // [1024,1024]

    char* ws = (char*)d_ws;
    unsigned short* xb    = (unsigned short*)(ws);                       // 8 MB
    unsigned short* wqkvT = (unsigned short*)(ws + (8ull  << 20));       // 6 MB
    unsigned short* woutT = (unsigned short*)(ws + (14ull << 20));       // 2 MB
    unsigned short* qkv   = (unsigned short*)(ws + (16ull << 20));       // 24 MB
    unsigned short* Qb    = (unsigned short*)(ws + (40ull << 20));       // 8 MB
    unsigned short* Kb    = (unsigned short*)(ws + (48ull << 20));       // 8 MB
    unsigned short* VT    = (unsigned short*)(ws + (56ull << 20));       // 8 MB
    unsigned short* Oat   = (unsigned short*)(ws + (64ull << 20));       // 8 MB
    float* cosT           = (float*)(ws + (72ull << 20));                // 256 KB
    float* sinT           = (float*)(ws + (72ull << 20) + (256u << 10)); // 256 KB

    rope_table_kernel<<<256, 256, 0, stream>>>(cosT, sinT);
    cast_x_kernel<<<4096, 256, 0, stream>>>(x, xb);
    transpose_cast_kernel<<<dim3(96, 32), dim3(32, 8), 0, stream>>>(wqkv, wqkvT, 1024, 3072);
    transpose_cast_kernel<<<dim3(32, 32), dim3(32, 8), 0, stream>>>(wout, woutT, 1024, 1024);
    gemm_bt_kernel<true><<<dim3(24, 32), 256, 0, stream>>>(xb, wqkvT, qkv, 4096, 3072, 1024);
    rope_split_kernel<<<16384, 256, 0, stream>>>(qkv, cosT, sinT, Qb, Kb, VT);
    flash_attn_kernel<<<dim3(16, 16, 2), 256, 0, stream>>>(Qb, Kb, VT, Oat);
    gemm_bt_kernel<false><<<dim3(8, 32), 256, 0, stream>>>(Oat, woutT, d_out, 4096, 1024, 1024);
}

// Round 3
// 182.566 us; speedup vs baseline: 1.8861x; 1.1244x over previous
//
#include <hip/hip_runtime.h>

typedef __attribute__((ext_vector_type(8))) short short8;
typedef __attribute__((ext_vector_type(4))) float f32x4;
typedef __attribute__((ext_vector_type(16))) float f32x16;

__device__ __forceinline__ unsigned short f2bf(float f) {
    unsigned u = __builtin_bit_cast(unsigned, f);
    u += 0x7FFFu + ((u >> 16) & 1u);
    return (unsigned short)(u >> 16);
}
__device__ __forceinline__ float bf2f(unsigned short b) {
    unsigned u = ((unsigned)b) << 16;
    return __builtin_bit_cast(float, u);
}
__device__ __forceinline__ short8 ld_frag(const uint4* p, int idx16) {
    return __builtin_bit_cast(short8, p[idx16]);
}
__device__ __forceinline__ unsigned packbf(float a, float b) {
    return (unsigned)f2bf(a) | ((unsigned)f2bf(b) << 16);
}
// async global->LDS, 16B per lane; lds base must be wave-uniform (HW adds lane*16)
__device__ __forceinline__ void gload_lds16(const void* g, void* l) {
    __builtin_amdgcn_global_load_lds((const __attribute__((address_space(1))) void*)g,
                                     (__attribute__((address_space(3))) void*)l, 16, 0, 0);
}

// ---------------- RoPE table: cos/sin [2048][32] fp32 ----------------
__global__ void rope_table_kernel(float* cosT, float* sinT) {
    int idx = blockIdx.x * 256 + threadIdx.x;
    int s = idx >> 5, i = idx & 31;
    float inv = powf(10000.f, -(float)i / 32.f);
    float ang = (float)s * inv;
    cosT[idx] = cosf(ang);
    sinT[idx] = sinf(ang);
}

// ---------------- cast x (fp32) -> bf16 ----------------
__global__ void cast_x_kernel(const float* __restrict__ x, unsigned short* __restrict__ xb) {
    int i = blockIdx.x * 256 + threadIdx.x;
    float4 v = reinterpret_cast<const float4*>(x)[i];
    ushort4 o;
    o.x = f2bf(v.x); o.y = f2bf(v.y); o.z = f2bf(v.z); o.w = f2bf(v.w);
    reinterpret_cast<ushort4*>(xb)[i] = o;
}

// ---------------- transpose + cast: in [R][C] fp32 -> out [C][R] bf16 ----------------
__global__ void transpose_cast_kernel(const float* __restrict__ in, unsigned short* __restrict__ out,
                                      int R, int C) {
    __shared__ float t[32][33];
    int c0 = blockIdx.x * 32, r0 = blockIdx.y * 32;
    int tx = threadIdx.x, ty = threadIdx.y;       // 32 x 8
    for (int i = 0; i < 4; ++i)
        t[ty + i * 8][tx] = in[(size_t)(r0 + ty + i * 8) * C + c0 + tx];
    __syncthreads();
    for (int i = 0; i < 4; ++i)
        out[(size_t)(c0 + ty + i * 8) * R + r0 + tx] = f2bf(t[tx][ty + i * 8]);
}

// ---------------- bf16 GEMM: A[M][K] x Bt[N][K]^T -> C[M][128*NF/4 per block] ----------------
template <bool OUT_BF16, int NF>
__global__ __launch_bounds__(256) void gemm_bt_kernel(const unsigned short* __restrict__ A,
                                                      const unsigned short* __restrict__ Bt,
                                                      void* __restrict__ Cout,
                                                      int M, int N, int K) {
    constexpr int BN = NF * 32;
    __shared__ __align__(16) unsigned short As[128 * 32];
    __shared__ __align__(16) unsigned short Bs[BN * 32];
    int tid = threadIdx.x;
    int lane = tid & 63;
    int w = tid >> 6;
    int wm = w >> 1, wn = w & 1;
    int m0 = blockIdx.y * 128, n0 = blockIdx.x * BN;
    int rq = lane >> 4, cl = lane & 15;

    f32x4 acc[4][NF] = {};
    const uint4* As4 = reinterpret_cast<const uint4*>(As);
    const uint4* Bs4 = reinterpret_cast<const uint4*>(Bs);

    for (int k0 = 0; k0 < K; k0 += 32) {
        __syncthreads();
        #pragma unroll
        for (int i = 0; i < 2; ++i) {
            int c = i * 256 + tid;
            int r = c >> 2, cc = c & 3;
            gload_lds16(A + (size_t)(m0 + r) * K + k0 + cc * 8,
                        (char*)As + (size_t)(i * 256 + w * 64) * 16);
        }
        #pragma unroll
        for (int i = 0; i < NF / 2; ++i) {
            int c = i * 256 + tid;
            int r = c >> 2, cc = c & 3;
            gload_lds16(Bt + (size_t)(n0 + r) * K + k0 + cc * 8,
                        (char*)Bs + (size_t)(i * 256 + w * 64) * 16);
        }
        __syncthreads();
        short8 af[4], bfr[NF];
        #pragma unroll
        for (int mf = 0; mf < 4; ++mf) {
            int row = wm * 64 + mf * 16 + cl;
            af[mf] = ld_frag(As4, row * 4 + rq);
        }
        #pragma unroll
        for (int nf = 0; nf < NF; ++nf) {
            int row = wn * (NF * 16) + nf * 16 + cl;
            bfr[nf] = ld_frag(Bs4, row * 4 + rq);
        }
        __builtin_amdgcn_s_setprio(1);
        #pragma unroll
        for (int mf = 0; mf < 4; ++mf)
            #pragma unroll
            for (int nf = 0; nf < NF; ++nf)
                acc[mf][nf] = __builtin_amdgcn_mfma_f32_16x16x32_bf16(af[mf], bfr[nf], acc[mf][nf], 0, 0, 0);
        __builtin_amdgcn_s_setprio(0);
    }
    #pragma unroll
    for (int mf = 0; mf < 4; ++mf)
        #pragma unroll
        for (int nf = 0; nf < NF; ++nf)
            #pragma unroll
            for (int r = 0; r < 4; ++r) {
                size_t row = m0 + wm * 64 + mf * 16 + rq * 4 + r;
                size_t col = n0 + wn * (NF * 16) + nf * 16 + cl;
                float v = acc[mf][nf][r];
                if (OUT_BF16)
                    ((unsigned short*)Cout)[row * N + col] = f2bf(v);
                else
                    ((float*)Cout)[row * N + col] = v;
            }
}

// ---------------- RoPE + split: Q scaled by 0.125*log2(e); V handled separately ----------------
__global__ void rope_split_kernel(const unsigned short* __restrict__ qkv,
                                  const float* __restrict__ cosT, const float* __restrict__ sinT,
                                  unsigned short* __restrict__ Qb, unsigned short* __restrict__ Kb) {
    const float QSCALE = 0.125f * 1.44269504088896f;
    int t = blockIdx.x * 256 + threadIdx.x;       // 4M threads
    int d = t & 63;
    int h = (t >> 6) & 15;
    int s = (t >> 10) & 2047;
    int b = t >> 21;
    size_t rowb = ((size_t)(b * 2048 + s)) * 3072;
    int col = h * 64 + d;
    int f = d & 31;
    float cs = cosT[s * 32 + f], sn = sinT[s * 32 + f];
    int d2 = (d < 32) ? d + 32 : d - 32;

    float q  = bf2f(qkv[rowb + col]);
    float qp = bf2f(qkv[rowb + h * 64 + d2]);
    float qo = (d < 32) ? q * cs - qp * sn : q * cs + qp * sn;
    float k  = bf2f(qkv[rowb + 1024 + col]);
    float kp = bf2f(qkv[rowb + 1024 + h * 64 + d2]);
    float ko = (d < 32) ? k * cs - kp * sn : k * cs + kp * sn;

    size_t ho = (size_t)(b * 16 + h);
    Qb[(ho * 2048 + s) * 64 + d] = f2bf(qo * QSCALE);
    Kb[(ho * 2048 + s) * 64 + d] = f2bf(ko);
}

// ---------------- V transpose: qkv v-part [b][s][h*64+d] -> VT [b,h][64 d][2048 s] ----------------
__global__ void v_transpose_kernel(const unsigned short* __restrict__ qkv,
                                   unsigned short* __restrict__ VT) {
    __shared__ unsigned short t[64][65];
    int s0 = blockIdx.x * 64;
    int h = blockIdx.y, bb = blockIdx.z;
    int tx = threadIdx.x, ty = threadIdx.y;       // 64 x 4
    #pragma unroll
    for (int i = 0; i < 16; ++i) {
        int r = ty + i * 4;
        t[r][tx] = qkv[((size_t)(bb * 2048 + s0 + r)) * 3072 + 2048 + h * 64 + tx];
    }
    __syncthreads();
    size_t ho = (size_t)(bb * 16 + h);
    #pragma unroll
    for (int i = 0; i < 16; ++i) {
        int d = ty + i * 4;
        VT[(ho * 64 + d) * 2048 + s0 + tx] = t[tx][d];
    }
}

// ---------------- flash attention v3: dbuf LDS via global_load_lds, defer-max ----------------
__device__ __forceinline__ short8 lds_frag(const unsigned short* base, int row, int colByte) {
    return __builtin_bit_cast(short8,
        *reinterpret_cast<const uint4*>(reinterpret_cast<const char*>(base) + row * 128 +
                                        (colByte ^ ((row & 7) << 4))));
}

__global__ __launch_bounds__(256, 2) void flash_attn_kernel(const unsigned short* __restrict__ Qb,
                                                            const unsigned short* __restrict__ Kb,
                                                            const unsigned short* __restrict__ VT,
                                                            unsigned short* __restrict__ Oattn) {
    const int S = 2048;
    __shared__ __align__(16) unsigned short Ks[2][64 * 64];
    __shared__ __align__(16) unsigned short Vs[2][64 * 64];
    int tid = threadIdx.x, lane = tid & 63, w = tid >> 6;
    int gid = blockIdx.x;
    int hh = gid & 31;                 // head id -> XCD = hh%8 (L2 locality)
    int chunk = 15 - (gid >> 5);       // heavy chunks dispatch first
    int q0 = chunk * 128;
    size_t headOff = (size_t)hh * S * 64;
    const unsigned short* Kg = Kb + headOff;
    const unsigned short* Vg = VT + headOff;      // [64][S]
    int l31 = lane & 31, hi = lane >> 5;
    int qw = q0 + w * 32;
    int qrow = qw + l31;

    // staging constants (per thread, fixed across tiles)
    int sc[2], sr[2];
    #pragma unroll
    for (int i = 0; i < 2; ++i) {
        int c = i * 256 + tid;
        int r = c >> 3, c8 = c & 7;
        sr[i] = r;
        sc[i] = (c8 ^ (r & 7)) * 8;    // pre-swizzled column (elems)
    }

    // Q fragments (Q pre-scaled by 0.125*log2e)
    short8 qf[4];
    {
        const uint4* Qg4 = reinterpret_cast<const uint4*>(Qb + headOff);
        #pragma unroll
        for (int c = 0; c < 4; ++c)
            qf[c] = ld_frag(Qg4, qrow * 8 + c * 2 + hi);
    }

    f32x16 oacc0 = {}, oacc1 = {};
    float m = -INFINITY, l = 0.f;
    int nk = (q0 + 128) / 64;
    int qmax_w = qw + 32;

    // prologue: stage tile 0 into buf 0
    #pragma unroll
    for (int i = 0; i < 2; ++i) {
        gload_lds16(Kg + sr[i] * 64 + sc[i], (char*)&Ks[0][0] + (size_t)(i * 256 + w * 64) * 16);
        gload_lds16(Vg + (size_t)sr[i] * S + sc[i], (char*)&Vs[0][0] + (size_t)(i * 256 + w * 64) * 16);
    }
    __syncthreads();
    int cur = 0;

    for (int kt = 0; kt < nk; ++kt) {
        int kv0 = kt * 64;
        if (kt + 1 < nk) {            // issue next tile's loads (hide latency under compute)
            int kvn = kv0 + 64;
            #pragma unroll
            for (int i = 0; i < 2; ++i) {
                gload_lds16(Kg + (kvn + sr[i]) * 64 + sc[i],
                            (char*)&Ks[cur ^ 1][0] + (size_t)(i * 256 + w * 64) * 16);
                gload_lds16(Vg + (size_t)sr[i] * S + kvn + sc[i],
                            (char*)&Vs[cur ^ 1][0] + (size_t)(i * 256 + w * 64) * 16);
            }
        }
        if (kv0 < qmax_w) {
            const unsigned short* Kt = &Ks[cur][0];
            const unsigned short* Vt = &Vs[cur][0];
            // QK^T (swapped): lane holds S^T[kv][qrow], kv = kv0 + {l31, l31+32}
            f32x16 s0 = {}, s1 = {};
            __builtin_amdgcn_s_setprio(1);
            #pragma unroll
            for (int c = 0; c < 4; ++c) {
                short8 a0 = lds_frag(Kt, l31, c * 32 + hi * 16);
                short8 a1 = lds_frag(Kt, 32 + l31, c * 32 + hi * 16);
                s0 = __builtin_amdgcn_mfma_f32_32x32x16_bf16(a0, qf[c], s0, 0, 0, 0);
                s1 = __builtin_amdgcn_mfma_f32_32x32x16_bf16(a1, qf[c], s1, 0, 0, 0);
            }
            __builtin_amdgcn_s_setprio(0);

            // mask + tile max (scores already in exp2 domain)
            float tm = -INFINITY;
            if (kv0 + 63 <= qw) {
                #pragma unroll
                for (int r = 0; r < 16; ++r)
                    tm = fmaxf(tm, fmaxf(s0[r], s1[r]));
            } else {
                #pragma unroll
                for (int r = 0; r < 16; ++r) {
                    int kva = kv0 + (r & 3) + 8 * (r >> 2) + 4 * hi;
                    float v0 = (kva <= qrow) ? s0[r] : -INFINITY;
                    float v1 = (kva + 32 <= qrow) ? s1[r] : -INFINITY;
                    s0[r] = v0; s1[r] = v1;
                    tm = fmaxf(tm, fmaxf(v0, v1));
                }
            }
            tm = fmaxf(tm, __shfl_xor(tm, 32));
            // defer-max: rescale only when max grew by >8 (P bounded by 2^8)
            if (!__all(tm - m <= 8.f)) {
                float mn = fmaxf(m, tm);
                float al = exp2f(m - mn);
                m = mn;
                l *= al;
                #pragma unroll
                for (int r = 0; r < 16; ++r) { oacc0[r] *= al; oacc1[r] *= al; }
            }
            float rs = 0.f;
            #pragma unroll
            for (int r = 0; r < 16; ++r) {
                s0[r] = exp2f(s0[r] - m);
                s1[r] = exp2f(s1[r] - m);
                rs += s0[r] + s1[r];
            }
            rs += __shfl_xor(rs, 32);
            l += rs;

            // P -> bf16 B-fragments: pack, then exchange only the crossing half (8 shfl)
            unsigned wd[16];
            #pragma unroll
            for (int i = 0; i < 8; ++i) {
                wd[i]     = packbf(s0[2 * i], s0[2 * i + 1]);
                wd[i + 8] = packbf(s1[2 * i], s1[2 * i + 1]);
            }
            const int m0i[8] = {0, 1, 4, 5, 8, 9, 12, 13};
            const int m1i[8] = {2, 3, 6, 7, 10, 11, 14, 15};
            unsigned r8[8];
            #pragma unroll
            for (int i = 0; i < 8; ++i)
                r8[i] = (unsigned)__shfl_xor((int)(hi ? wd[m0i[i]] : wd[m1i[i]]), 32);
            short8 pb[4];
            #pragma unroll
            for (int j = 0; j < 4; ++j) {
                uint4 lo = {wd[m0i[2 * j]], wd[m0i[2 * j + 1]], r8[2 * j], r8[2 * j + 1]};
                uint4 hv = {r8[2 * j], r8[2 * j + 1], wd[m1i[2 * j]], wd[m1i[2 * j + 1]]};
                pb[j] = __builtin_bit_cast(short8, hi ? hv : lo);
            }

            // PV (swapped): oacc = V^T x P^T
            __builtin_amdgcn_s_setprio(1);
            #pragma unroll
            for (int t = 0; t < 4; ++t) {
                short8 a0 = lds_frag(Vt, l31, t * 32 + hi * 16);
                short8 a1 = lds_frag(Vt, 32 + l31, t * 32 + hi * 16);
                oacc0 = __builtin_amdgcn_mfma_f32_32x32x16_bf16(a0, pb[t], oacc0, 0, 0, 0);
                oacc1 = __builtin_amdgcn_mfma_f32_32x32x16_bf16(a1, pb[t], oacc1, 0, 0, 0);
            }
            __builtin_amdgcn_s_setprio(0);
        }
        __syncthreads();               // drains next-tile loads; all waves done reading cur
        cur ^= 1;
    }

    // epilogue: out[qrow][d] = oacc[d][qrow] / l
    float invl = 1.f / l;
    size_t orow = ((size_t)((hh >> 4) * 2048 + qrow)) * 1024 + (hh & 15) * 64;
    #pragma unroll
    for (int du = 0; du < 2; ++du) {
        const f32x16& oa = du ? oacc1 : oacc0;
        #pragma unroll
        for (int g = 0; g < 4; ++g) {
            ushort4 o;
            o.x = f2bf(oa[4 * g + 0] * invl);
            o.y = f2bf(oa[4 * g + 1] * invl);
            o.z = f2bf(oa[4 * g + 2] * invl);
            o.w = f2bf(oa[4 * g + 3] * invl);
            int d = du * 32 + 4 * hi + 8 * g;
            *reinterpret_cast<ushort4*>(Oattn + orow + d) = o;
        }
    }
}

extern "C" void kernel_launch(void* const* d_in, const int* in_sizes, int n_in,
                              void* d_out, int out_size, void* d_ws, size_t ws_size,
                              hipStream_t stream) {
    const float* x    = (const float*)d_in[0];   // [2,2048,1024]
    const float* wqkv = (const float*)d_in[1];   // [1024,3072]
    const float* wout = (const float*)d_in[2];   // [1024,1024]

    char* ws = (char*)d_ws;
    unsigned short* xb    = (unsigned short*)(ws);                       // 8 MB
    unsigned short* wqkvT = (unsigned short*)(ws + (8ull  << 20));       // 6 MB
    unsigned short* woutT = (unsigned short*)(ws + (14ull << 20));       // 2 MB
    unsigned short* qkv   = (unsigned short*)(ws + (16ull << 20));       // 24 MB
    unsigned short* Qb    = (unsigned short*)(ws + (40ull << 20));       // 8 MB
    unsigned short* Kb    = (unsigned short*)(ws + (48ull << 20));       // 8 MB
    unsigned short* VT    = (unsigned short*)(ws + (56ull << 20));       // 8 MB
    unsigned short* Oat   = (unsigned short*)(ws + (64ull << 20));       // 8 MB
    float* cosT           = (float*)(ws + (72ull << 20));                // 256 KB
    float* sinT           = (float*)(ws + (72ull << 20) + (256u << 10)); // 256 KB

    rope_table_kernel<<<256, 256, 0, stream>>>(cosT, sinT);
    cast_x_kernel<<<4096, 256, 0, stream>>>(x, xb);
    transpose_cast_kernel<<<dim3(96, 32), dim3(32, 8), 0, stream>>>(wqkv, wqkvT, 1024, 3072);
    transpose_cast_kernel<<<dim3(32, 32), dim3(32, 8), 0, stream>>>(wout, woutT, 1024, 1024);
    gemm_bt_kernel<true, 4><<<dim3(24, 32), 256, 0, stream>>>(xb, wqkvT, qkv, 4096, 3072, 1024);
    rope_split_kernel<<<16384, 256, 0, stream>>>(qkv, cosT, sinT, Qb, Kb);
    v_transpose_kernel<<<dim3(32, 16, 2), dim3(64, 4), 0, stream>>>(qkv, VT);
    flash_attn_kernel<<<512, 256, 0, stream>>>(Qb, Kb, VT, Oat);
    gemm_bt_kernel<false, 2><<<dim3(16, 32), 256, 0, stream>>>(Oat, woutT, d_out, 4096, 1024, 1024);
}